// Round 9
// baseline (602.751 us; speedup 1.0000x reference)
//
#include <hip/hip_runtime.h>
#include <hip/hip_cooperative_groups.h>
#include <math.h>

// Match numpy/XLA fp32 semantics: no compiler-introduced FMA contraction.
#pragma clang fp contract(off)

namespace cg = cooperative_groups;

#define KCAP 64                     // output neighbor cap (reference K)
#define GMAX 54                     // max grid resolution per dim
#define MAXCELLS (GMAX*GMAX*GMAX)   // 157464
#define XMIN -8.0f
#define SPAN 16.0f
#define NBLOCKS 1024                // 4 blocks/CU -> cooperative co-residency safe
#define NTHREADS 256

// Same grid derivation as the passing round-5 kernels. cell >= 2r guarantees
// any true neighbor lies in the +-1 bin neighborhood even under fp rounding.
__device__ __forceinline__ void grid_params(const float* __restrict__ radius_p,
                                            float* rr, float* cell, int* G) {
  float r = radius_p[0];
  *rr = r * r;
  float c = fmaxf(2.0f * r, SPAN / (float)GMAX);
  int g = (int)ceilf(SPAN / c);
  *G = g < 1 ? 1 : (g > GMAX ? GMAX : g);
  *cell = c;
}

__device__ __forceinline__ int bin1(float v, float cell, int G) {
  int b = (int)floorf((v - XMIN) / cell);
  return b < 0 ? 0 : (b > G - 1 ? G - 1 : b);
}

// One cooperative dispatch, six phases separated by grid.sync():
//  0 zero cellCnt+cursor;  1 bin-count (atomics);  2 wave-per-row alloc
//  (shuffle scan + cursor atomic, x-contiguous rows);  3 scatter (x,y,z,p2);
//  4 wave-per-query search (9 merged ranges, ballot-compact, bitonic sort
//    by (d2,idx) = jax.lax.top_k tie-break);  5 block-0 row_splits scan.
// All per-pair arithmetic bit-identical to the passing round-5 kernels.
__global__ __launch_bounds__(NTHREADS) void fused_kernel(
    const float* __restrict__ pts, const float* __restrict__ queries,
    const float* __restrict__ radius_p, float* __restrict__ out_idx,
    float* __restrict__ out_rs, float* __restrict__ out_dist,
    int* __restrict__ wsbase, int N, int M) {
  __shared__ float d2buf[NTHREADS / 64][KCAP];
  __shared__ int idxbuf[NTHREADS / 64][KCAP];
  __shared__ int wsum[NTHREADS / 64];

  // Workspace layout (float4 first for 16B alignment).
  float4* sortedPts = (float4*)wsbase;      // N
  int* sortedIdx = (int*)(sortedPts + N);   // N
  int* cellCnt = sortedIdx + N;             // MAXCELLS
  int* cellStart = cellCnt + MAXCELLS;      // MAXCELLS
  int* cellEnd = cellStart + MAXCELLS;      // MAXCELLS
  int* cursor = cellEnd + MAXCELLS;         // 1
  int* pointBin = cursor + 1;               // N
  int* pointPos = pointBin + N;             // N
  int* qcounts = pointPos + N;              // M

  cg::grid_group grid = cg::this_grid();
  const int tid = blockIdx.x * NTHREADS + threadIdx.x;
  const int nthreads = gridDim.x * NTHREADS;
  const int lane = threadIdx.x & 63;
  const int wv = threadIdx.x >> 6;
  const int gwave = tid >> 6;
  const int nwaves = nthreads >> 6;

  float rr, cell; int G;
  grid_params(radius_p, &rr, &cell, &G);
  const int ncells = G * G * G;

  // ---- phase 0: zero counts + cursor ----
  for (int i = tid; i < ncells; i += nthreads) cellCnt[i] = 0;
  if (tid == 0) cursor[0] = 0;
  grid.sync();

  // ---- phase 1: histogram points into cells ----
  for (int i = tid; i < N; i += nthreads) {
    float x = pts[3 * i], y = pts[3 * i + 1], z = pts[3 * i + 2];
    int b = (bin1(z, cell, G) * G + bin1(y, cell, G)) * G + bin1(x, cell, G);
    pointBin[i] = b;
    pointPos[i] = atomicAdd(&cellCnt[b], 1);
  }
  grid.sync();

  // ---- phase 2: one wave per (y,z) row: contiguous alloc of G cells ----
  for (int row = gwave; row < G * G; row += nwaves) {
    int base = row * G;
    int c = (lane < G) ? cellCnt[base + lane] : 0;
    int pre = c;  // inclusive scan over 64 lanes
    for (int off = 1; off < 64; off <<= 1) {
      int v = __shfl_up(pre, off);
      if (lane >= off) pre += v;
    }
    int total = __shfl(pre, 63);
    int start = 0;
    if (lane == 63) start = atomicAdd(cursor, total);
    start = __shfl(start, 63);
    if (lane < G) {
      cellStart[base + lane] = start + pre - c;
      cellEnd[base + lane] = start + pre;
    }
  }
  grid.sync();

  // ---- phase 3: scatter points as (x,y,z,p2) in cell order ----
  for (int i = tid; i < N; i += nthreads) {
    float x = pts[3 * i], y = pts[3 * i + 1], z = pts[3 * i + 2];
    float p2 = (x * x + y * y) + z * z;  // numpy sum order, no fma
    int dst = cellStart[pointBin[i]] + pointPos[i];
    sortedPts[dst] = make_float4(x, y, z, p2);
    sortedIdx[dst] = i;
  }
  grid.sync();

  // ---- phase 4: one wave per query ----
  for (int q = gwave; q < M; q += nwaves) {
    float qx = queries[3 * q], qy = queries[3 * q + 1], qz = queries[3 * q + 2];
    float q2 = (qx * qx + qy * qy) + qz * qz;  // numpy sum order, no fma
    int cx = bin1(qx, cell, G), cy = bin1(qy, cell, G), cz = bin1(qz, cell, G);
    int xlo = max(cx - 1, 0), xhi = min(cx + 1, G - 1);
    int cnt = 0;
    for (int dz = -1; dz <= 1; ++dz) {
      int zz = cz + dz;
      if (zz < 0 || zz >= G) continue;
      for (int dy = -1; dy <= 1; ++dy) {
        int yy = cy + dy;
        if (yy < 0 || yy >= G) continue;
        int rowb = (zz * G + yy) * G;
        int s = cellStart[rowb + xlo];
        int e = cellEnd[rowb + xhi];
        for (int b = s; b < e; b += 64) {
          int i = b + lane;
          bool valid = i < e;
          float4 p = valid ? sortedPts[i] : make_float4(0.f, 0.f, 0.f, INFINITY);
          // Bit-identical per-pair arithmetic (all passing rounds):
          float dot = fmaf(p.z, qz, fmaf(p.y, qy, p.x * qx));
          float sdd = q2 + p.w;
          float d2 = fmaf(dot, -2.0f, sdd);   // == sdd - 2*dot exactly
          bool hit = valid && (d2 <= rr);     // unclamped == clamped membership
          unsigned long long mask = __ballot(hit);
          int pos = cnt + __popcll(mask & ((1ull << lane) - 1ull));
          if (hit && pos < KCAP) {
            d2buf[wv][pos] = fmaxf(d2, 0.0f);  // clamp on store
            idxbuf[wv][pos] = sortedIdx[i];
          }
          cnt += __popcll(mask);
        }
      }
    }
    int c64 = cnt < KCAP ? cnt : KCAP;
    float d2 = (lane < c64) ? d2buf[wv][lane] : INFINITY;
    int idx = (lane < c64) ? idxbuf[wv][lane] : 0x7fffffff;
    for (int k = 2; k <= 64; k <<= 1) {
      for (int jj = k >> 1; jj > 0; jj >>= 1) {
        float od2 = __shfl_xor(d2, jj);
        int oidx = __shfl_xor(idx, jj);
        bool up = ((lane & k) == 0);
        bool lower = ((lane & jj) == 0);
        bool takeMin = (lower == up);
        bool oLess = (od2 < d2) || (od2 == d2 && oidx < idx);
        bool take = takeMin ? oLess : !oLess;
        if (take) { d2 = od2; idx = oidx; }
      }
    }
    out_idx[q * KCAP + lane] = (lane < c64) ? (float)idx : -1.0f;
    out_dist[q * KCAP + lane] = (lane < c64) ? d2 : 0.0f;
    if (lane == 0) qcounts[q] = c64;
  }
  grid.sync();

  // ---- phase 5: row_splits scan (block 0 only; 256 threads x 32 counts) ----
  if (blockIdx.x == 0) {
    const int t = threadIdx.x;
    const int base = t * 32;
    int s = 0;
#pragma unroll 4
    for (int j = 0; j < 32; ++j) {
      int i = base + j;
      s += (i < M) ? qcounts[i] : 0;
    }
    int pre = s;
    for (int off = 1; off < 64; off <<= 1) {
      int v = __shfl_up(pre, off);
      if (lane >= off) pre += v;
    }
    if (lane == 63) wsum[wv] = pre;
    __syncthreads();
    int woff = 0;
    for (int w = 0; w < wv; ++w) woff += wsum[w];
    int run = woff + pre - s;
    if (t == 0) out_rs[0] = 0.0f;
#pragma unroll 4
    for (int j = 0; j < 32; ++j) {
      int i = base + j;
      if (i < M) {
        run += qcounts[i];
        out_rs[1 + i] = (float)run;
      }
    }
  }
}

extern "C" void kernel_launch(void* const* d_in, const int* in_sizes, int n_in,
                              void* d_out, int out_size, void* d_ws, size_t ws_size,
                              hipStream_t stream) {
  const float* points = (const float*)d_in[0];
  const float* queries = (const float*)d_in[1];
  const float* radius = (const float*)d_in[2];
  int N = in_sizes[0] / 3;  // 16384
  int M = in_sizes[1] / 3;  // 8192

  float* out = (float*)d_out;
  float* out_idx = out;                    // [M, 64]
  float* out_rs = out + (size_t)M * KCAP;  // [M+1]
  float* out_dist = out_rs + (M + 1);      // [M, 64]
  int* wsbase = (int*)d_ws;

  void* args[] = {(void*)&points, (void*)&queries, (void*)&radius,
                  (void*)&out_idx, (void*)&out_rs, (void*)&out_dist,
                  (void*)&wsbase, (void*)&N, (void*)&M};
  hipLaunchCooperativeKernel((const void*)fused_kernel, dim3(NBLOCKS),
                             dim3(NTHREADS), args, 0, stream);
}

// Round 11
// 98.311 us; speedup vs baseline: 6.1311x; 6.1311x over previous
//
#include <hip/hip_runtime.h>
#include <math.h>

// Match numpy/XLA fp32 semantics: no compiler-introduced FMA contraction.
#pragma clang fp contract(off)

#define KCAP 64       // output neighbor cap (reference K)
#define GMAX 54       // max grid resolution per dim
#define XMIN -8.0f
#define SPAN 16.0f

// Same grid derivation as the passing round-5 kernels. cell >= 2r guarantees
// any true neighbor lies in the +-1 bin neighborhood even under fp rounding.
__device__ __forceinline__ void grid_params(const float* __restrict__ radius_p,
                                            float* rr, float* cell, int* G) {
  float r = radius_p[0];
  *rr = r * r;
  float c = fmaxf(2.0f * r, SPAN / (float)GMAX);
  int g = (int)ceilf(SPAN / c);
  *G = g < 1 ? 1 : (g > GMAX ? GMAX : g);
  *cell = c;
}

__device__ __forceinline__ int bin1(float v, float cell, int G) {
  int b = (int)floorf((v - XMIN) / cell);
  return b < 0 ? 0 : (b > G - 1 ? G - 1 : b);
}

// Dispatch 1: 2D (y,z) counting sort, one block per z-row, fixed per-row
// capacity N (region base z*N) -> no global cursor, no memset, no cross-block
// communication. Rows y-contiguous => query reads 3 contiguous ranges.
// Two passes over points: count -> wave-scan -> scatter (x,y,z,p2).
__global__ __launch_bounds__(1024) void build_kernel(
    const float* __restrict__ pts, const float* __restrict__ radius_p,
    float4* __restrict__ sortedPts, int* __restrict__ sortedIdx,
    int* __restrict__ rowStart, int* __restrict__ rowEnd,
    int* __restrict__ done, int N) {
  __shared__ int cnt[GMAX];
  __shared__ int cur[GMAX];
  float rr, cell; int G;
  grid_params(radius_p, &rr, &cell, &G);
  const int z = blockIdx.x;
  if (z == 0 && threadIdx.x == 0) *done = 0;  // reset last-block counter
  if (z >= G) return;

  for (int y = threadIdx.x; y < G; y += 1024) cnt[y] = 0;
  __syncthreads();

  // Pass A: count this z-row's points per y-bin.
  for (int i = threadIdx.x; i < N; i += 1024) {
    float yv = pts[3 * i + 1], zv = pts[3 * i + 2];
    if (bin1(zv, cell, G) == z) atomicAdd(&cnt[bin1(yv, cell, G)], 1);
  }
  __syncthreads();

  // Exclusive scan of <=54 bins by wave 0; publish absolute row ranges.
  if (threadIdx.x < 64) {
    int lane = threadIdx.x;
    int c = (lane < G) ? cnt[lane] : 0;
    int pre = c;
    for (int off = 1; off < 64; off <<= 1) {
      int v = __shfl_up(pre, off);
      if (lane >= off) pre += v;
    }
    if (lane < G) {
      cur[lane] = pre - c;                    // exclusive prefix = cursor
      rowStart[z * G + lane] = z * N + (pre - c);
      rowEnd[z * G + lane] = z * N + pre;
    }
  }
  __syncthreads();

  // Pass B: scatter into cell-ordered storage.
  for (int i = threadIdx.x; i < N; i += 1024) {
    float xv = pts[3 * i], yv = pts[3 * i + 1], zv = pts[3 * i + 2];
    if (bin1(zv, cell, G) == z) {
      int pos = atomicAdd(&cur[bin1(yv, cell, G)], 1);
      float p2 = (xv * xv + yv * yv) + zv * zv;  // numpy sum order, no fma
      sortedPts[z * N + pos] = make_float4(xv, yv, zv, p2);
      sortedIdx[z * N + pos] = i;
    }
  }
}

// Dispatch 2: wave per query, 3 contiguous candidate ranges, ballot-compact,
// 64-lane bitonic sort by (d2, idx) (= jax.lax.top_k tie-break). The LAST
// block (device-scope atomic ticket + threadfence) runs the row-splits scan.
__global__ __launch_bounds__(256) void query_kernel(
    const float* __restrict__ queries, const float* __restrict__ radius_p,
    const float4* __restrict__ sortedPts, const int* __restrict__ sortedIdx,
    const int* __restrict__ rowStart, const int* __restrict__ rowEnd,
    float* __restrict__ out_idx, float* __restrict__ out_dist,
    float* __restrict__ out_rs, int* __restrict__ qcounts,
    int* __restrict__ done, int N, int M) {
  __shared__ float d2buf[4][KCAP];
  __shared__ int idxbuf[4][KCAP];
  __shared__ int wsum[4];
  __shared__ int amLastS;
  const int lane = threadIdx.x & 63;
  const int wv = threadIdx.x >> 6;
  const int q = blockIdx.x * 4 + wv;
  float rr, cell; int G;
  grid_params(radius_p, &rr, &cell, &G);

  if (q < M) {
    float qx = queries[3 * q], qy = queries[3 * q + 1], qz = queries[3 * q + 2];
    float q2 = (qx * qx + qy * qy) + qz * qz;  // numpy sum order, no fma
    int cy = bin1(qy, cell, G), cz = bin1(qz, cell, G);
    int ylo = max(cy - 1, 0), yhi = min(cy + 1, G - 1);
    int cnt = 0;
    for (int dz = -1; dz <= 1; ++dz) {
      int zz = cz + dz;
      if (zz < 0 || zz >= G) continue;
      int s = rowStart[zz * G + ylo];
      int e = rowEnd[zz * G + yhi];
      for (int b = s; b < e; b += 64) {
        int i = b + lane;
        bool valid = i < e;
        float4 p = valid ? sortedPts[i] : make_float4(0.f, 0.f, 0.f, INFINITY);
        // Bit-identical per-pair arithmetic (all passing rounds):
        float dot = fmaf(p.z, qz, fmaf(p.y, qy, p.x * qx));
        float sdd = q2 + p.w;
        float d2 = fmaf(dot, -2.0f, sdd);   // == sdd - 2*dot exactly
        bool hit = valid && (d2 <= rr);     // unclamped == clamped membership
        unsigned long long mask = __ballot(hit);
        int pos = cnt + __popcll(mask & ((1ull << lane) - 1ull));
        if (hit && pos < KCAP) {
          d2buf[wv][pos] = fmaxf(d2, 0.0f);  // clamp on store
          idxbuf[wv][pos] = sortedIdx[i];
        }
        cnt += __popcll(mask);
      }
    }
    int c64 = cnt < KCAP ? cnt : KCAP;
    float d2 = (lane < c64) ? d2buf[wv][lane] : INFINITY;
    int idx = (lane < c64) ? idxbuf[wv][lane] : 0x7fffffff;
    for (int k = 2; k <= 64; k <<= 1) {
      for (int jj = k >> 1; jj > 0; jj >>= 1) {
        float od2 = __shfl_xor(d2, jj);
        int oidx = __shfl_xor(idx, jj);
        bool up = ((lane & k) == 0);
        bool lower = ((lane & jj) == 0);
        bool takeMin = (lower == up);
        bool oLess = (od2 < d2) || (od2 == d2 && oidx < idx);
        bool take = takeMin ? oLess : !oLess;
        if (take) { d2 = od2; idx = oidx; }
      }
    }
    out_idx[q * KCAP + lane] = (lane < c64) ? (float)idx : -1.0f;
    out_dist[q * KCAP + lane] = (lane < c64) ? d2 : 0.0f;
    if (lane == 0) qcounts[q] = c64;
  }
  __syncthreads();

  // Last-block ticket: the final block to arrive performs the scan.
  if (threadIdx.x == 0) {
    __threadfence();  // release our qcounts writes device-wide
    unsigned int t = atomicAdd((unsigned int*)done, 1u);
    amLastS = (t == (unsigned int)(gridDim.x - 1)) ? 1 : 0;
  }
  __syncthreads();
  if (amLastS) {
    __threadfence();  // acquire all blocks' qcounts
    const int t = threadIdx.x;
    const int base = t * 32;
    int s = 0;
#pragma unroll 4
    for (int j = 0; j < 32; ++j) {
      int i = base + j;
      s += (i < M) ? qcounts[i] : 0;
    }
    int pre = s;
    for (int off = 1; off < 64; off <<= 1) {
      int v = __shfl_up(pre, off);
      if (lane >= off) pre += v;
    }
    if (lane == 63) wsum[wv] = pre;
    __syncthreads();
    int woff = 0;
    for (int w = 0; w < wv; ++w) woff += wsum[w];
    int run = woff + pre - s;
    if (t == 0) out_rs[0] = 0.0f;
#pragma unroll 4
    for (int j = 0; j < 32; ++j) {
      int i = base + j;
      if (i < M) {
        run += qcounts[i];
        out_rs[1 + i] = (float)run;
      }
    }
  }
}

extern "C" void kernel_launch(void* const* d_in, const int* in_sizes, int n_in,
                              void* d_out, int out_size, void* d_ws, size_t ws_size,
                              hipStream_t stream) {
  const float* points = (const float*)d_in[0];
  const float* queries = (const float*)d_in[1];
  const float* radius = (const float*)d_in[2];
  const int N = in_sizes[0] / 3;  // 16384
  const int M = in_sizes[1] / 3;  // 8192

  float* out = (float*)d_out;
  float* out_idx = out;                    // [M, 64]
  float* out_rs = out + (size_t)M * KCAP;  // [M+1]
  float* out_dist = out_rs + (M + 1);      // [M, 64]

  // Workspace layout (float4 first for 16B alignment). ~18 MB total.
  float4* sortedPts = (float4*)d_ws;                      // GMAX*N
  int* sortedIdx = (int*)(sortedPts + (size_t)GMAX * N);  // GMAX*N
  int* rowStart = sortedIdx + (size_t)GMAX * N;           // GMAX*GMAX
  int* rowEnd = rowStart + GMAX * GMAX;                   // GMAX*GMAX
  int* qcounts = rowEnd + GMAX * GMAX;                    // M
  int* done = qcounts + M;                                // 1

  build_kernel<<<GMAX, 1024, 0, stream>>>(points, radius, sortedPts, sortedIdx,
                                          rowStart, rowEnd, done, N);
  const int qblocks = (M + 3) / 4;  // 2048
  query_kernel<<<qblocks, 256, 0, stream>>>(queries, radius, sortedPts,
                                            sortedIdx, rowStart, rowEnd,
                                            out_idx, out_dist, out_rs, qcounts,
                                            done, N, M);
}